// Round 4
// baseline (809.430 us; speedup 1.0000x reference)
//
#include <hip/hip_runtime.h>

constexpr int BLK = 256;
static inline int nblk(long long total, int blk = BLK) { return (int)((total + blk - 1) / blk); }

typedef float f32x4 __attribute__((ext_vector_type(4)));

// ---------- utility ----------
__global__ void k_zero_i32(int* __restrict__ p, int n) {
    int i = blockIdx.x * blockDim.x + threadIdx.x;
    if (i < n) p[i] = 0;
}

__global__ void k_copy_i32(const int* __restrict__ a, int* __restrict__ b, int n) {
    int i = blockIdx.x * blockDim.x + threadIdx.x;
    if (i < n) b[i] = a[i];
}

// ---------- CSR build ----------
__global__ void k_hist(const int* __restrict__ dst, int* __restrict__ cnt, int E) {
    int e = blockIdx.x * blockDim.x + threadIdx.x;
    if (e < E) {
        int d = __builtin_nontemporal_load(&dst[e]);
        atomicAdd(&cnt[d], 1);
    }
}

// block-level exclusive scan (Hillis-Steele in LDS), emits block sums
__global__ void k_scan_block(int* __restrict__ data, int* __restrict__ sums, int n) {
    __shared__ int s[256];
    int i = blockIdx.x * 256 + threadIdx.x;
    int v = (i < n) ? data[i] : 0;
    s[threadIdx.x] = v;
    __syncthreads();
    for (int off = 1; off < 256; off <<= 1) {
        int t = (threadIdx.x >= off) ? s[threadIdx.x - off] : 0;
        __syncthreads();
        s[threadIdx.x] += t;
        __syncthreads();
    }
    if (i < n) data[i] = s[threadIdx.x] - v;          // exclusive
    if (threadIdx.x == 255) sums[blockIdx.x] = s[255]; // block total
}

// single-block exclusive scan of the block sums (n <= 512)
__global__ void k_scan_sums(int* __restrict__ sums, int n) {
    __shared__ int s[512];
    int i = threadIdx.x;
    int v = (i < n) ? sums[i] : 0;
    s[i] = v;
    __syncthreads();
    for (int off = 1; off < 512; off <<= 1) {
        int t = (i >= off) ? s[i - off] : 0;
        __syncthreads();
        s[i] += t;
        __syncthreads();
    }
    if (i < n) sums[i] = s[i] - v; // exclusive
}

__global__ void k_scan_add(int* __restrict__ data, const int* __restrict__ sums, int n) {
    int i = blockIdx.x * 256 + threadIdx.x;
    if (i < n) data[i] += sums[blockIdx.x];
}

__global__ void k_dinv(const int* __restrict__ rowptr, float* __restrict__ dinv, int N) {
    int i = blockIdx.x * blockDim.x + threadIdx.x;
    if (i < N) dinv[i] = rsqrtf((float)(rowptr[i + 1] - rowptr[i] + 1)); // +1 self-loop
}

// fill using pre-copied cursor (= rowptr): atomic gives the final index directly
__global__ void k_fill(const int* __restrict__ src, const int* __restrict__ dst,
                       int* __restrict__ cursor, int* __restrict__ col, int E) {
    int e = blockIdx.x * blockDim.x + threadIdx.x;
    if (e < E) {
        int d = __builtin_nontemporal_load(&dst[e]);
        int s = __builtin_nontemporal_load(&src[e]);
        int pos = atomicAdd(&cursor[d], 1);
        __builtin_nontemporal_store(s, &col[pos]);
    }
}

// ---------- gather aggregation: out[i] = dinv[i]*(dinv[i]*feat[i] + sum_s dinv[s]*feat[s]) ----------
template<int D, int BLKA>
__global__ void k_agg(const int* __restrict__ col, const int* __restrict__ rowptr,
                      const float* __restrict__ dinv, const float* __restrict__ feat,
                      float* __restrict__ out, int N) {
    constexpr int NPB = BLKA / D;
    int g = threadIdx.x / D, d = threadIdx.x % D;
    int i = blockIdx.x * NPB + g;
    if (i >= N) return;
    int beg = rowptr[i], end = rowptr[i + 1];
    float di = dinv[i];
    float acc0 = di * feat[(size_t)i * D + d]; // self-loop term
    float acc1 = 0.0f;
    int e = beg;
    for (; e + 3 < end; e += 4) { // 4-wide, dual accumulators for load ILP
        int s0 = col[e], s1 = col[e + 1], s2 = col[e + 2], s3 = col[e + 3];
        float w0 = dinv[s0], w1 = dinv[s1], w2 = dinv[s2], w3 = dinv[s3];
        float f0 = feat[(size_t)s0 * D + d], f1 = feat[(size_t)s1 * D + d];
        float f2 = feat[(size_t)s2 * D + d], f3 = feat[(size_t)s3 * D + d];
        acc0 = fmaf(w0, f0, acc0);
        acc1 = fmaf(w1, f1, acc1);
        acc0 = fmaf(w2, f2, acc0);
        acc1 = fmaf(w3, f3, acc1);
    }
    for (; e < end; ++e) {
        int s = col[e];
        acc0 = fmaf(dinv[s], feat[(size_t)s * D + d], acc0);
    }
    __builtin_nontemporal_store(di * (acc0 + acc1), &out[(size_t)i * D + d]);
}

// ---------- fused: L1 aggregate (D=1) + transform 1->16 + ReLU ----------
__global__ void k_agg1_t16(const int* __restrict__ col, const int* __restrict__ rowptr,
                           const float* __restrict__ dinv, const float* __restrict__ x,
                           const float* __restrict__ W1, const float* __restrict__ b1,
                           float* __restrict__ out, int N) {
    __shared__ float sW[16], sb[16];
    if (threadIdx.x < 16) { sW[threadIdx.x] = W1[threadIdx.x]; sb[threadIdx.x] = b1[threadIdx.x]; }
    __syncthreads();
    int i = blockIdx.x * blockDim.x + threadIdx.x;
    if (i >= N) return;
    int beg = rowptr[i], end = rowptr[i + 1];
    float di = dinv[i];
    float acc0 = di * x[i], acc1 = 0.0f;
    int e = beg;
    for (; e + 3 < end; e += 4) {
        int s0 = col[e], s1 = col[e + 1], s2 = col[e + 2], s3 = col[e + 3];
        acc0 = fmaf(dinv[s0], x[s0], acc0);
        acc1 = fmaf(dinv[s1], x[s1], acc1);
        acc0 = fmaf(dinv[s2], x[s2], acc0);
        acc1 = fmaf(dinv[s3], x[s3], acc1);
    }
    for (; e < end; ++e) acc0 = fmaf(dinv[col[e]], x[col[e]], acc0);
    float a = di * (acc0 + acc1);
    f32x4* op = (f32x4*)(out + (size_t)i * 16);
    #pragma unroll
    for (int q = 0; q < 4; ++q) {
        f32x4 v;
        v.x = fmaxf(fmaf(a, sW[4 * q + 0], sb[4 * q + 0]), 0.0f);
        v.y = fmaxf(fmaf(a, sW[4 * q + 1], sb[4 * q + 1]), 0.0f);
        v.z = fmaxf(fmaf(a, sW[4 * q + 2], sb[4 * q + 2]), 0.0f);
        v.w = fmaxf(fmaf(a, sW[4 * q + 3], sb[4 * q + 3]), 0.0f);
        __builtin_nontemporal_store(v, &op[q]);
    }
}

// ---------- dense transform: out = act(in @ W + b) ----------
template<int DIN, int DOUT, bool BIAS, bool RELU>
__global__ void k_transform(const float* __restrict__ in, const float* __restrict__ W,
                            const float* __restrict__ b, float* __restrict__ out, int N) {
    __shared__ float sW[DIN * DOUT];
    __shared__ float sb[DOUT];
    for (int k = threadIdx.x; k < DIN * DOUT; k += blockDim.x) sW[k] = W[k];
    if (BIAS) for (int k = threadIdx.x; k < DOUT; k += blockDim.x) sb[k] = b[k];
    __syncthreads();
    long long gid = (long long)blockIdx.x * blockDim.x + threadIdx.x;
    if (gid >= (long long)N * DOUT) return;
    int i = (int)(gid / DOUT), j = (int)(gid % DOUT);
    const float* row = in + (long long)i * DIN;
    float acc = BIAS ? sb[j] : 0.0f;
    #pragma unroll
    for (int d = 0; d < DIN; ++d) acc = fmaf(row[d], sW[d * DOUT + j], acc);
    out[gid] = RELU ? fmaxf(acc, 0.0f) : acc;
}

// ---------- final: out = log_softmax(out + b), 5 classes, in-place ----------
__global__ void k_logsoftmax5(float* __restrict__ io, const float* __restrict__ b, int N) {
    int i = blockIdx.x * blockDim.x + threadIdx.x;
    if (i >= N) return;
    float v[5];
    #pragma unroll
    for (int j = 0; j < 5; ++j) v[j] = io[(long long)i * 5 + j] + b[j];
    float m = v[0];
    #pragma unroll
    for (int j = 1; j < 5; ++j) m = fmaxf(m, v[j]);
    float s = 0.0f;
    #pragma unroll
    for (int j = 0; j < 5; ++j) s += expf(v[j] - m);
    float ls = m + logf(s);
    #pragma unroll
    for (int j = 0; j < 5; ++j) io[(long long)i * 5 + j] = v[j] - ls;
}

extern "C" void kernel_launch(void* const* d_in, const int* in_sizes, int n_in,
                              void* d_out, int out_size, void* d_ws, size_t ws_size,
                              hipStream_t stream) {
    const float* x  = (const float*)d_in[0];
    const int*   ei = (const int*)d_in[1];   // [2, E] int32
    const float* W1 = (const float*)d_in[2];
    const float* b1 = (const float*)d_in[3];
    const float* W2 = (const float*)d_in[4];
    const float* b2 = (const float*)d_in[5];
    const float* W3 = (const float*)d_in[6];
    const float* b3 = (const float*)d_in[7];
    const float* W4 = (const float*)d_in[8];
    const float* b4 = (const float*)d_in[9];

    const int N = in_sizes[0];        // 100000
    const int E = in_sizes[1] / 2;    // 3200000
    float* out = (float*)d_out;
    const int* src = ei;
    const int* dst = ei + E;
    (void)n_in; (void)out_size; (void)ws_size;

    // ---- workspace layout (256B aligned chunks) ----
    auto align_up = [](size_t v) { return (v + 255) & ~(size_t)255; };
    char* p = (char*)d_ws;
    int*   rowptr = (int*)p;   p += align_up(sizeof(int) * (size_t)(N + 1));
    int*   cursor = (int*)p;   p += align_up(sizeof(int) * (size_t)N);
    int*   sums   = (int*)p;   p += align_up(sizeof(int) * 512);
    float* dinv   = (float*)p; p += align_up(sizeof(float) * (size_t)N);
    int*   col    = (int*)p;   p += align_up(sizeof(int) * (size_t)E);
    float* bufA   = (float*)p; p += align_up(sizeof(float) * (size_t)N * 64);
    float* bufB   = (float*)p; p += align_up(sizeof(float) * (size_t)N * 64);

    const int nScan = N + 1;                 // include trailing 0 so rowptr[N] = E after scan
    const int nScanBlk = nblk(nScan);

    // ---- CSR build ----
    k_zero_i32<<<nblk(nScan), BLK, 0, stream>>>(rowptr, nScan);
    k_hist<<<nblk(E), BLK, 0, stream>>>(dst, rowptr, E);
    k_scan_block<<<nScanBlk, 256, 0, stream>>>(rowptr, sums, nScan);
    k_scan_sums<<<1, 512, 0, stream>>>(sums, nScanBlk);
    k_scan_add<<<nScanBlk, 256, 0, stream>>>(rowptr, sums, nScan);
    k_dinv<<<nblk(N), BLK, 0, stream>>>(rowptr, dinv, N);
    k_copy_i32<<<nblk(N), BLK, 0, stream>>>(rowptr, cursor, N);
    k_fill<<<nblk(E), BLK, 0, stream>>>(src, dst, cursor, col, E);

    // ---- Layer 1: fused aggregate (D=1) + 1->16 + ReLU ----
    k_agg1_t16<<<nblk(N), BLK, 0, stream>>>(col, rowptr, dinv, x, W1, b1, bufB, N);

    // ---- Layer 2: aggregate (D=16) then 16->64 (ReLU) ----
    k_agg<16, 256><<<nblk(N, 16), 256, 0, stream>>>(col, rowptr, dinv, bufB, bufA, N);
    k_transform<16, 64, true, true><<<nblk((long long)N * 64), BLK, 0, stream>>>(bufA, W2, b2, bufB, N);

    // ---- Layer 3: aggregate (D=64) then 64->64 (ReLU) ----
    k_agg<64, 256><<<nblk(N, 4), 256, 0, stream>>>(col, rowptr, dinv, bufB, bufA, N);
    k_transform<64, 64, true, true><<<nblk((long long)N * 64), BLK, 0, stream>>>(bufA, W3, b3, bufB, N);

    // ---- Layer 4: 64->5 (no bias) then aggregate (D=5) into out, log_softmax ----
    k_transform<64, 5, false, false><<<nblk((long long)N * 5), BLK, 0, stream>>>(bufB, W4, nullptr, bufA, N);
    k_agg<5, 320><<<nblk(N, 64), 320, 0, stream>>>(col, rowptr, dinv, bufA, out, N);
    k_logsoftmax5<<<nblk(N), BLK, 0, stream>>>(out, b4, N);
}

// Round 5
// 457.150 us; speedup vs baseline: 1.7706x; 1.7706x over previous
//
#include <hip/hip_runtime.h>

constexpr int BLK = 256;
static inline int nblk(long long total, int blk = BLK) { return (int)((total + blk - 1) / blk); }

// Bucketing: SPAN = 256 nodes/bucket -> bucket = dst>>8, local = dst&255.
// Packed edge: (local<<17) | src  (src < 2^17 since N=100000 < 131072).
// NB = (N+255)>>8 = 391 for N=100000; shared arrays sized for NB <= 400.
constexpr int MAXNB = 400;
constexpr int CAP = 12288;  // LDS edge capacity in k_build (mean 8184, sigma ~90)

// ---------- utility ----------
__global__ void k_zero_i32(int* __restrict__ p, int n) {
    int i = blockIdx.x * blockDim.x + threadIdx.x;
    if (i < n) p[i] = 0;
}

// ---------- Pass A: bucket histogram ----------
template<int ITER>
__global__ void k_bucket_hist(const int* __restrict__ dst, int* __restrict__ bcnt, int E, int NB) {
    __shared__ int h[MAXNB];
    for (int t = threadIdx.x; t < NB; t += blockDim.x) h[t] = 0;
    __syncthreads();
    long long b0 = (long long)blockIdx.x * blockDim.x * ITER;
    for (int k = 0; k < ITER; ++k) {
        long long e = b0 + (long long)k * blockDim.x + threadIdx.x;
        if (e < E) atomicAdd(&h[dst[e] >> 8], 1);
    }
    __syncthreads();
    for (int t = threadIdx.x; t < NB; t += blockDim.x)
        if (h[t]) atomicAdd(&bcnt[t], h[t]);
}

// ---------- bucket exclusive scan (1 block, NB <= 512); also inits bucket cursors ----------
__global__ void k_bucket_scan(const int* __restrict__ bcnt, int* __restrict__ bbase,
                              int* __restrict__ bcur, int NB) {
    __shared__ int s[512];
    int i = threadIdx.x;
    int v = (i < NB) ? bcnt[i] : 0;
    s[i] = v;
    __syncthreads();
    for (int off = 1; off < 512; off <<= 1) {
        int t = (i >= off) ? s[i - off] : 0;
        __syncthreads();
        s[i] += t;
        __syncthreads();
    }
    int ex = s[i] - v;  // exclusive
    if (i < NB) { bbase[i] = ex; bcur[i] = ex; }
    if (i == NB - 1) bbase[NB] = ex + v;  // = E
}

// ---------- Pass B: bin packed edges into bucket regions ----------
template<int ITER>
__global__ void k_bin(const int* __restrict__ src, const int* __restrict__ dst,
                      int* __restrict__ bcur, int* __restrict__ ebuf, int E, int NB) {
    __shared__ int cnt[MAXNB];
    __shared__ int basei[MAXNB];
    for (int t = threadIdx.x; t < NB; t += blockDim.x) cnt[t] = 0;
    __syncthreads();
    long long b0 = (long long)blockIdx.x * blockDim.x * ITER;
    for (int k = 0; k < ITER; ++k) {   // sweep 1: count
        long long e = b0 + (long long)k * blockDim.x + threadIdx.x;
        if (e < E) atomicAdd(&cnt[dst[e] >> 8], 1);
    }
    __syncthreads();
    for (int t = threadIdx.x; t < NB; t += blockDim.x) {  // reserve runs
        int c = cnt[t];
        basei[t] = c ? atomicAdd(&bcur[t], c) : 0;
    }
    __syncthreads();
    for (int t = threadIdx.x; t < NB; t += blockDim.x) cnt[t] = 0;  // reuse as cursor
    __syncthreads();
    for (int k = 0; k < ITER; ++k) {   // sweep 2: write
        long long e = b0 + (long long)k * blockDim.x + threadIdx.x;
        if (e < E) {
            int d = dst[e], s = src[e];
            int b = d >> 8;
            int pos = basei[b] + atomicAdd(&cnt[b], 1);
            ebuf[pos] = ((d & 255) << 17) | s;
        }
    }
}

// ---------- Pass C: per-bucket fused hist+scan -> rowptr, dinv, col ----------
__global__ __launch_bounds__(512) void k_build(const int* __restrict__ bbase,
                                               const int* __restrict__ ebuf,
                                               int* __restrict__ rowptr, float* __restrict__ dinv,
                                               int* __restrict__ col, int N) {
    __shared__ int eLds[CAP];
    __shared__ int cnt[256];
    __shared__ int scn[256];
    int b = blockIdx.x;
    int base = bbase[b];
    int size = bbase[b + 1] - base;
    for (int t = threadIdx.x; t < 256; t += blockDim.x) cnt[t] = 0;
    for (int k = threadIdx.x; k < size && k < CAP; k += blockDim.x) eLds[k] = ebuf[base + k];
    __syncthreads();
    for (int k = threadIdx.x; k < size; k += blockDim.x) {   // hist
        int pv = (k < CAP) ? eLds[k] : ebuf[base + k];
        atomicAdd(&cnt[pv >> 17], 1);
    }
    __syncthreads();
    if (threadIdx.x < 256) scn[threadIdx.x] = cnt[threadIdx.x];
    __syncthreads();
    for (int off = 1; off < 256; off <<= 1) {   // inclusive scan
        int t = (threadIdx.x < 256 && threadIdx.x >= off) ? scn[threadIdx.x - off] : 0;
        __syncthreads();
        if (threadIdx.x < 256) scn[threadIdx.x] += t;
        __syncthreads();
    }
    int node0 = b << 8;
    if (threadIdx.x < 256) {
        int node = node0 + threadIdx.x;
        int ex = scn[threadIdx.x] - cnt[threadIdx.x];  // exclusive
        if (node <= N) rowptr[node] = base + ex;       // node==N -> rowptr[N]=E
        if (node < N)  dinv[node] = rsqrtf((float)(cnt[threadIdx.x] + 1)); // +1 self-loop
        cnt[threadIdx.x] = ex;                          // repurpose as cursor
    }
    __syncthreads();
    for (int k = threadIdx.x; k < size; k += blockDim.x) {   // fill
        int pv = (k < CAP) ? eLds[k] : ebuf[base + k];
        int pos = atomicAdd(&cnt[pv >> 17], 1);
        col[base + pos] = pv & 0x1FFFF;
    }
}

// ---------- gather aggregation: out[i] = dinv[i]*(dinv[i]*feat[i] + sum_s dinv[s]*feat[s]) ----------
template<int D, int BLKA>
__global__ void k_agg(const int* __restrict__ col, const int* __restrict__ rowptr,
                      const float* __restrict__ dinv, const float* __restrict__ feat,
                      float* __restrict__ out, int N) {
    constexpr int NPB = BLKA / D;
    int g = threadIdx.x / D, d = threadIdx.x % D;
    int i = blockIdx.x * NPB + g;
    if (i >= N) return;
    int beg = rowptr[i], end = rowptr[i + 1];
    float di = dinv[i];
    float acc0 = di * feat[(size_t)i * D + d]; // self-loop term
    float acc1 = 0.0f;
    int e = beg;
    for (; e + 3 < end; e += 4) {
        int s0 = col[e], s1 = col[e + 1], s2 = col[e + 2], s3 = col[e + 3];
        float w0 = dinv[s0], w1 = dinv[s1], w2 = dinv[s2], w3 = dinv[s3];
        float f0 = feat[(size_t)s0 * D + d], f1 = feat[(size_t)s1 * D + d];
        float f2 = feat[(size_t)s2 * D + d], f3 = feat[(size_t)s3 * D + d];
        acc0 = fmaf(w0, f0, acc0);
        acc1 = fmaf(w1, f1, acc1);
        acc0 = fmaf(w2, f2, acc0);
        acc1 = fmaf(w3, f3, acc1);
    }
    for (; e < end; ++e) {
        int s = col[e];
        acc0 = fmaf(dinv[s], feat[(size_t)s * D + d], acc0);
    }
    out[(size_t)i * D + d] = di * (acc0 + acc1);
}

// ---------- fused: L1 aggregate (D=1) + transform 1->16 + ReLU ----------
__global__ void k_agg1_t16(const int* __restrict__ col, const int* __restrict__ rowptr,
                           const float* __restrict__ dinv, const float* __restrict__ x,
                           const float* __restrict__ W1, const float* __restrict__ b1,
                           float* __restrict__ out, int N) {
    __shared__ float sW[16], sb[16];
    if (threadIdx.x < 16) { sW[threadIdx.x] = W1[threadIdx.x]; sb[threadIdx.x] = b1[threadIdx.x]; }
    __syncthreads();
    int i = blockIdx.x * blockDim.x + threadIdx.x;
    if (i >= N) return;
    int beg = rowptr[i], end = rowptr[i + 1];
    float di = dinv[i];
    float acc0 = di * x[i], acc1 = 0.0f;
    int e = beg;
    for (; e + 3 < end; e += 4) {
        int s0 = col[e], s1 = col[e + 1], s2 = col[e + 2], s3 = col[e + 3];
        acc0 = fmaf(dinv[s0], x[s0], acc0);
        acc1 = fmaf(dinv[s1], x[s1], acc1);
        acc0 = fmaf(dinv[s2], x[s2], acc0);
        acc1 = fmaf(dinv[s3], x[s3], acc1);
    }
    for (; e < end; ++e) acc0 = fmaf(dinv[col[e]], x[col[e]], acc0);
    float a = di * (acc0 + acc1);
    float* op = out + (size_t)i * 16;
    #pragma unroll
    for (int j = 0; j < 16; ++j)
        op[j] = fmaxf(fmaf(a, sW[j], sb[j]), 0.0f);
}

// ---------- dense transform: out = act(in @ W + b) ----------
template<int DIN, int DOUT, bool BIAS, bool RELU>
__global__ void k_transform(const float* __restrict__ in, const float* __restrict__ W,
                            const float* __restrict__ b, float* __restrict__ out, int N) {
    __shared__ float sW[DIN * DOUT];
    __shared__ float sb[DOUT];
    for (int k = threadIdx.x; k < DIN * DOUT; k += blockDim.x) sW[k] = W[k];
    if (BIAS) for (int k = threadIdx.x; k < DOUT; k += blockDim.x) sb[k] = b[k];
    __syncthreads();
    long long gid = (long long)blockIdx.x * blockDim.x + threadIdx.x;
    if (gid >= (long long)N * DOUT) return;
    int i = (int)(gid / DOUT), j = (int)(gid % DOUT);
    const float* row = in + (long long)i * DIN;
    float acc = BIAS ? sb[j] : 0.0f;
    #pragma unroll
    for (int d = 0; d < DIN; ++d) acc = fmaf(row[d], sW[d * DOUT + j], acc);
    out[gid] = RELU ? fmaxf(acc, 0.0f) : acc;
}

// ---------- final: out = log_softmax(out + b), 5 classes, in-place ----------
__global__ void k_logsoftmax5(float* __restrict__ io, const float* __restrict__ b, int N) {
    int i = blockIdx.x * blockDim.x + threadIdx.x;
    if (i >= N) return;
    float v[5];
    #pragma unroll
    for (int j = 0; j < 5; ++j) v[j] = io[(long long)i * 5 + j] + b[j];
    float m = v[0];
    #pragma unroll
    for (int j = 1; j < 5; ++j) m = fmaxf(m, v[j]);
    float s = 0.0f;
    #pragma unroll
    for (int j = 0; j < 5; ++j) s += expf(v[j] - m);
    float ls = m + logf(s);
    #pragma unroll
    for (int j = 0; j < 5; ++j) io[(long long)i * 5 + j] = v[j] - ls;
}

extern "C" void kernel_launch(void* const* d_in, const int* in_sizes, int n_in,
                              void* d_out, int out_size, void* d_ws, size_t ws_size,
                              hipStream_t stream) {
    const float* x  = (const float*)d_in[0];
    const int*   ei = (const int*)d_in[1];   // [2, E] int32
    const float* W1 = (const float*)d_in[2];
    const float* b1 = (const float*)d_in[3];
    const float* W2 = (const float*)d_in[4];
    const float* b2 = (const float*)d_in[5];
    const float* W3 = (const float*)d_in[6];
    const float* b3 = (const float*)d_in[7];
    const float* W4 = (const float*)d_in[8];
    const float* b4 = (const float*)d_in[9];

    const int N = in_sizes[0];        // 100000
    const int E = in_sizes[1] / 2;    // 3200000
    float* out = (float*)d_out;
    const int* src = ei;
    const int* dst = ei + E;
    (void)n_in; (void)out_size; (void)ws_size;

    const int NB = (N + 255) >> 8;    // 391 buckets

    // ---- workspace layout (256B aligned chunks) ----
    auto align_up = [](size_t v) { return (v + 255) & ~(size_t)255; };
    char* p = (char*)d_ws;
    int*   rowptr = (int*)p;   p += align_up(sizeof(int) * (size_t)(N + 1));
    float* dinv   = (float*)p; p += align_up(sizeof(float) * (size_t)N);
    int*   bcnt   = (int*)p;   p += align_up(sizeof(int) * (MAXNB + 1));
    int*   bbase  = (int*)p;   p += align_up(sizeof(int) * (MAXNB + 1));
    int*   bcur   = (int*)p;   p += align_up(sizeof(int) * (MAXNB + 1));
    int*   col    = (int*)p;   p += align_up(sizeof(int) * (size_t)E);
    float* bufA   = (float*)p; p += align_up(sizeof(float) * (size_t)N * 64);
    float* bufB   = (float*)p; p += align_up(sizeof(float) * (size_t)N * 64);
    int*   ebuf   = (int*)bufA;  // alias: ebuf (E ints) dead before bufA's first use

    // ---- CSR build (bucketed, scatter confined to LDS / L2-windows) ----
    constexpr int ITER = 32;                       // 8192 edges per block
    const int gBkt = nblk(E, BLK * ITER);          // 391 blocks
    k_zero_i32<<<nblk(NB), BLK, 0, stream>>>(bcnt, NB);
    k_bucket_hist<ITER><<<gBkt, BLK, 0, stream>>>(dst, bcnt, E, NB);
    k_bucket_scan<<<1, 512, 0, stream>>>(bcnt, bbase, bcur, NB);
    k_bin<ITER><<<gBkt, BLK, 0, stream>>>(src, dst, bcur, ebuf, E, NB);
    k_build<<<NB, 512, 0, stream>>>(bbase, ebuf, rowptr, dinv, col, N);

    // ---- Layer 1: fused aggregate (D=1) + 1->16 + ReLU ----
    k_agg1_t16<<<nblk(N), BLK, 0, stream>>>(col, rowptr, dinv, x, W1, b1, bufB, N);

    // ---- Layer 2: aggregate (D=16) then 16->64 (ReLU) ----
    k_agg<16, 256><<<nblk(N, 16), 256, 0, stream>>>(col, rowptr, dinv, bufB, bufA, N);
    k_transform<16, 64, true, true><<<nblk((long long)N * 64), BLK, 0, stream>>>(bufA, W2, b2, bufB, N);

    // ---- Layer 3: aggregate (D=64) then 64->64 (ReLU) ----
    k_agg<64, 256><<<nblk(N, 4), 256, 0, stream>>>(col, rowptr, dinv, bufB, bufA, N);
    k_transform<64, 64, true, true><<<nblk((long long)N * 64), BLK, 0, stream>>>(bufA, W3, b3, bufB, N);

    // ---- Layer 4: 64->5 (no bias) then aggregate (D=5) into out, log_softmax ----
    k_transform<64, 5, false, false><<<nblk((long long)N * 5), BLK, 0, stream>>>(bufB, W4, nullptr, bufA, N);
    k_agg<5, 320><<<nblk(N, 64), 320, 0, stream>>>(col, rowptr, dinv, bufA, out, N);
    k_logsoftmax5<<<nblk(N), BLK, 0, stream>>>(out, b4, N);
}

// Round 6
// 362.091 us; speedup vs baseline: 2.2354x; 1.2625x over previous
//
#include <hip/hip_runtime.h>
#include <hip/hip_fp16.h>

constexpr int BLK = 256;
static inline int nblk(long long total, int blk = BLK) { return (int)((total + blk - 1) / blk); }

constexpr int MAXNB = 400;
constexpr int CAP = 12288;  // LDS edge capacity in k_build (mean 8184, sigma ~90)

__device__ inline float2 h2f2(unsigned u) {
    __half2 h = *reinterpret_cast<__half2*>(&u);
    return __half22float2(h);
}
__device__ inline unsigned f2h2(float a, float b) {
    __half2 h = __floats2half2_rn(a, b);
    return *reinterpret_cast<unsigned*>(&h);
}

// ---------- utility ----------
__global__ void k_zero_i32(int* __restrict__ p, int n) {
    int i = blockIdx.x * blockDim.x + threadIdx.x;
    if (i < n) p[i] = 0;
}

// ---------- Pass A: bucket histogram ----------
template<int ITER>
__global__ void k_bucket_hist(const int* __restrict__ dst, int* __restrict__ bcnt, int E, int NB) {
    __shared__ int h[MAXNB];
    for (int t = threadIdx.x; t < NB; t += blockDim.x) h[t] = 0;
    __syncthreads();
    long long b0 = (long long)blockIdx.x * blockDim.x * ITER;
    for (int k = 0; k < ITER; ++k) {
        long long e = b0 + (long long)k * blockDim.x + threadIdx.x;
        if (e < E) atomicAdd(&h[dst[e] >> 8], 1);
    }
    __syncthreads();
    for (int t = threadIdx.x; t < NB; t += blockDim.x)
        if (h[t]) atomicAdd(&bcnt[t], h[t]);
}

// ---------- bucket exclusive scan (1 block, NB <= 512); also inits bucket cursors ----------
__global__ void k_bucket_scan(const int* __restrict__ bcnt, int* __restrict__ bbase,
                              int* __restrict__ bcur, int NB) {
    __shared__ int s[512];
    int i = threadIdx.x;
    int v = (i < NB) ? bcnt[i] : 0;
    s[i] = v;
    __syncthreads();
    for (int off = 1; off < 512; off <<= 1) {
        int t = (i >= off) ? s[i - off] : 0;
        __syncthreads();
        s[i] += t;
        __syncthreads();
    }
    int ex = s[i] - v;  // exclusive
    if (i < NB) { bbase[i] = ex; bcur[i] = ex; }
    if (i == NB - 1) bbase[NB] = ex + v;  // = E
}

// ---------- Pass B: bin packed edges into bucket regions ----------
template<int ITER>
__global__ void k_bin(const int* __restrict__ src, const int* __restrict__ dst,
                      int* __restrict__ bcur, int* __restrict__ ebuf, int E, int NB) {
    __shared__ int cnt[MAXNB];
    __shared__ int basei[MAXNB];
    for (int t = threadIdx.x; t < NB; t += blockDim.x) cnt[t] = 0;
    __syncthreads();
    long long b0 = (long long)blockIdx.x * blockDim.x * ITER;
    for (int k = 0; k < ITER; ++k) {   // sweep 1: count
        long long e = b0 + (long long)k * blockDim.x + threadIdx.x;
        if (e < E) atomicAdd(&cnt[dst[e] >> 8], 1);
    }
    __syncthreads();
    for (int t = threadIdx.x; t < NB; t += blockDim.x) {  // reserve runs
        int c = cnt[t];
        basei[t] = c ? atomicAdd(&bcur[t], c) : 0;
    }
    __syncthreads();
    for (int t = threadIdx.x; t < NB; t += blockDim.x) cnt[t] = 0;  // reuse as cursor
    __syncthreads();
    for (int k = 0; k < ITER; ++k) {   // sweep 2: write
        long long e = b0 + (long long)k * blockDim.x + threadIdx.x;
        if (e < E) {
            int d = dst[e], s = src[e];
            int b = d >> 8;
            int pos = basei[b] + atomicAdd(&cnt[b], 1);
            ebuf[pos] = ((d & 255) << 17) | s;
        }
    }
}

// ---------- Pass C: per-bucket fused hist+scan -> rowptr, dinv, col ----------
__global__ __launch_bounds__(512) void k_build(const int* __restrict__ bbase,
                                               const int* __restrict__ ebuf,
                                               int* __restrict__ rowptr, float* __restrict__ dinv,
                                               int* __restrict__ col, int N) {
    __shared__ int eLds[CAP];
    __shared__ int cnt[256];
    __shared__ int scn[256];
    int b = blockIdx.x;
    int base = bbase[b];
    int size = bbase[b + 1] - base;
    for (int t = threadIdx.x; t < 256; t += blockDim.x) cnt[t] = 0;
    for (int k = threadIdx.x; k < size && k < CAP; k += blockDim.x) eLds[k] = ebuf[base + k];
    __syncthreads();
    for (int k = threadIdx.x; k < size; k += blockDim.x) {   // hist
        int pv = (k < CAP) ? eLds[k] : ebuf[base + k];
        atomicAdd(&cnt[pv >> 17], 1);
    }
    __syncthreads();
    if (threadIdx.x < 256) scn[threadIdx.x] = cnt[threadIdx.x];
    __syncthreads();
    for (int off = 1; off < 256; off <<= 1) {   // inclusive scan
        int t = (threadIdx.x < 256 && threadIdx.x >= off) ? scn[threadIdx.x - off] : 0;
        __syncthreads();
        if (threadIdx.x < 256) scn[threadIdx.x] += t;
        __syncthreads();
    }
    int node0 = b << 8;
    if (threadIdx.x < 256) {
        int node = node0 + threadIdx.x;
        int ex = scn[threadIdx.x] - cnt[threadIdx.x];  // exclusive
        if (node <= N) rowptr[node] = base + ex;       // node==N -> rowptr[N]=E
        if (node < N)  dinv[node] = rsqrtf((float)(cnt[threadIdx.x] + 1)); // +1 self-loop
        cnt[threadIdx.x] = ex;                          // repurpose as cursor
    }
    __syncthreads();
    for (int k = threadIdx.x; k < size; k += blockDim.x) {   // fill
        int pv = (k < CAP) ? eLds[k] : ebuf[base + k];
        int pos = atomicAdd(&cnt[pv >> 17], 1);
        col[base + pos] = pv & 0x1FFFF;
    }
}

// ---------- g0 = dinv * x ----------
__global__ void k_scale_x(const float* __restrict__ x, const float* __restrict__ dinv,
                          float* __restrict__ g0, int N) {
    int i = blockIdx.x * blockDim.x + threadIdx.x;
    if (i < N) g0[i] = dinv[i] * x[i];
}

// ---------- fused: L1 aggregate (D=1, pre-scaled) + 1->16 + ReLU -> packed half2, scaled ----------
__global__ void k_agg1_t16(const int* __restrict__ col, const int* __restrict__ rowptr,
                           const float* __restrict__ dinv, const float* __restrict__ g0,
                           const float* __restrict__ W1, const float* __restrict__ b1,
                           unsigned* __restrict__ g1, int N) {
    __shared__ float sW[16], sb[16];
    if (threadIdx.x < 16) { sW[threadIdx.x] = W1[threadIdx.x]; sb[threadIdx.x] = b1[threadIdx.x]; }
    __syncthreads();
    int i = blockIdx.x * blockDim.x + threadIdx.x;
    if (i >= N) return;
    int beg = rowptr[i], end = rowptr[i + 1];
    float acc0 = g0[i], acc1 = 0.0f;
    int e = beg;
    for (; e + 3 < end; e += 4) {
        int s0 = col[e], s1 = col[e + 1], s2 = col[e + 2], s3 = col[e + 3];
        acc0 += g0[s0]; acc1 += g0[s1]; acc0 += g0[s2]; acc1 += g0[s3];
    }
    for (; e < end; ++e) acc0 += g0[col[e]];
    float di = dinv[i];
    float a = di * (acc0 + acc1);
    unsigned up[8];
    #pragma unroll
    for (int q = 0; q < 8; ++q) {
        float r0 = fmaxf(fmaf(a, sW[2 * q + 0], sb[2 * q + 0]), 0.0f) * di;
        float r1 = fmaxf(fmaf(a, sW[2 * q + 1], sb[2 * q + 1]), 0.0f) * di;
        up[q] = f2h2(r0, r1);
    }
    uint4* op = (uint4*)(g1 + (size_t)i * 8);
    op[0] = make_uint4(up[0], up[1], up[2], up[3]);
    op[1] = make_uint4(up[4], up[5], up[6], up[7]);
}

// ---------- agg D=16 from packed half2 (pre-scaled): agg1[i] = di*(g1[i]+sum g1[s]) ----------
__global__ void k_aggh16(const int* __restrict__ col, const int* __restrict__ rowptr,
                         const float* __restrict__ dinv, const unsigned* __restrict__ g1,
                         float* __restrict__ agg1, int N) {
    int l = threadIdx.x & 7, g = threadIdx.x >> 3;   // 8 lanes/node, 32 nodes/block
    int i = blockIdx.x * 32 + g;
    if (i >= N) return;
    int beg = rowptr[i], end = rowptr[i + 1];
    float2 accA = h2f2(g1[(size_t)i * 8 + l]);   // self term
    float2 accB = {0.0f, 0.0f};
    int e = beg;
    for (; e + 1 < end; e += 2) {
        int s0 = col[e], s1 = col[e + 1];
        unsigned u0 = g1[(size_t)s0 * 8 + l], u1 = g1[(size_t)s1 * 8 + l];
        float2 f0 = h2f2(u0), f1 = h2f2(u1);
        accA.x += f0.x; accA.y += f0.y;
        accB.x += f1.x; accB.y += f1.y;
    }
    if (e < end) {
        float2 f = h2f2(g1[(size_t)col[e] * 8 + l]);
        accA.x += f.x; accA.y += f.y;
    }
    float di = dinv[i];
    float2 o; o.x = di * (accA.x + accB.x); o.y = di * (accA.y + accB.y);
    *(float2*)&agg1[(size_t)i * 16 + l * 2] = o;
}

// ---------- transform 16->64 (ReLU), output packed half2 scaled by dinv ----------
__global__ void k_t2(const float* __restrict__ agg1, const float* __restrict__ W2,
                     const float* __restrict__ b2, const float* __restrict__ dinv,
                     unsigned* __restrict__ g2, int N) {
    __shared__ float sW[16 * 64];
    __shared__ float sb[64];
    for (int k = threadIdx.x; k < 16 * 64; k += blockDim.x) sW[k] = W2[k];
    if (threadIdx.x < 64) sb[threadIdx.x] = b2[threadIdx.x];
    __syncthreads();
    long long gid = (long long)blockIdx.x * blockDim.x + threadIdx.x;
    if (gid >= (long long)N * 32) return;
    int i = (int)(gid >> 5), jj = (int)(gid & 31);
    int j0 = 2 * jj, j1 = 2 * jj + 1;
    const float* row = agg1 + (size_t)i * 16;
    float a0 = sb[j0], a1 = sb[j1];
    #pragma unroll
    for (int d = 0; d < 16; ++d) {
        float r = row[d];
        a0 = fmaf(r, sW[d * 64 + j0], a0);
        a1 = fmaf(r, sW[d * 64 + j1], a1);
    }
    float di = dinv[i];
    g2[gid] = f2h2(fmaxf(a0, 0.0f) * di, fmaxf(a1, 0.0f) * di);
}

// ---------- agg D=64 from packed half2 (uint2 loads, pre-scaled) ----------
__global__ void k_aggh64(const int* __restrict__ col, const int* __restrict__ rowptr,
                         const float* __restrict__ dinv, const uint2* __restrict__ g2,
                         float* __restrict__ agg2, int N) {
    int l = threadIdx.x & 15, g = threadIdx.x >> 4;  // 16 lanes/node, 16 nodes/block
    int i = blockIdx.x * 16 + g;
    if (i >= N) return;
    int beg = rowptr[i], end = rowptr[i + 1];
    uint2 us = g2[(size_t)i * 16 + l];               // self term
    float2 aA = h2f2(us.x), aB = h2f2(us.y);
    float2 bA = {0.0f, 0.0f}, bB = {0.0f, 0.0f};
    int e = beg;
    for (; e + 1 < end; e += 2) {
        int s0 = col[e], s1 = col[e + 1];
        uint2 u0 = g2[(size_t)s0 * 16 + l];
        uint2 u1 = g2[(size_t)s1 * 16 + l];
        float2 f;
        f = h2f2(u0.x); aA.x += f.x; aA.y += f.y;
        f = h2f2(u0.y); aB.x += f.x; aB.y += f.y;
        f = h2f2(u1.x); bA.x += f.x; bA.y += f.y;
        f = h2f2(u1.y); bB.x += f.x; bB.y += f.y;
    }
    if (e < end) {
        uint2 u = g2[(size_t)col[e] * 16 + l];
        float2 f;
        f = h2f2(u.x); aA.x += f.x; aA.y += f.y;
        f = h2f2(u.y); aB.x += f.x; aB.y += f.y;
    }
    float di = dinv[i];
    float4 o = make_float4(di * (aA.x + bA.x), di * (aA.y + bA.y),
                           di * (aB.x + bB.x), di * (aB.y + bB.y));
    *(float4*)&agg2[(size_t)i * 64 + l * 4] = o;
}

// ---------- fused transforms: h3 = relu(agg2 W3 + b3); zs = dinv * (h3 W4) ----------
__global__ __launch_bounds__(256) void k_t34(const float* __restrict__ agg2,
                                             const float* __restrict__ W3, const float* __restrict__ b3,
                                             const float* __restrict__ W4, const float* __restrict__ dinv,
                                             float* __restrict__ zs, int N) {
    __shared__ float sW3[64 * 64];
    __shared__ float sb3[64];
    __shared__ float sW4[64 * 5];
    __shared__ float row[4][64];
    __shared__ float h3[4][64];
    for (int k = threadIdx.x; k < 64 * 64; k += 256) sW3[k] = W3[k];
    if (threadIdx.x < 64) sb3[threadIdx.x] = b3[threadIdx.x];
    for (int k = threadIdx.x; k < 320; k += 256) sW4[k] = W4[k];
    __syncthreads();
    int g = threadIdx.x >> 6, j = threadIdx.x & 63;
    for (int r = 0; r < 8; ++r) {
        int i = blockIdx.x * 32 + r * 4 + g;
        bool ok = i < N;
        if (ok) row[g][j] = agg2[(size_t)i * 64 + j];
        __syncthreads();
        if (ok) {
            float a = sb3[j];
            #pragma unroll
            for (int d = 0; d < 64; ++d) a = fmaf(row[g][d], sW3[d * 64 + j], a);
            h3[g][j] = fmaxf(a, 0.0f);
        }
        __syncthreads();
        if (ok && j < 5) {
            float z = 0.0f;
            #pragma unroll
            for (int d = 0; d < 64; ++d) z = fmaf(h3[g][d], sW4[d * 5 + j], z);
            zs[(size_t)i * 5 + j] = dinv[i] * z;
        }
        __syncthreads();
    }
}

// ---------- agg D=5 f32 (pre-scaled) -> d_out ----------
__global__ void k_agg5(const int* __restrict__ col, const int* __restrict__ rowptr,
                       const float* __restrict__ dinv, const float* __restrict__ zs,
                       float* __restrict__ out, int N) {
    int g = threadIdx.x / 5, d = threadIdx.x % 5;   // 64 nodes per 320-block
    int i = blockIdx.x * 64 + g;
    if (i >= N || threadIdx.x >= 320) return;
    int beg = rowptr[i], end = rowptr[i + 1];
    float acc0 = zs[(size_t)i * 5 + d], acc1 = 0.0f;
    int e = beg;
    for (; e + 1 < end; e += 2) {
        int s0 = col[e], s1 = col[e + 1];
        acc0 += zs[(size_t)s0 * 5 + d];
        acc1 += zs[(size_t)s1 * 5 + d];
    }
    if (e < end) acc0 += zs[(size_t)col[e] * 5 + d];
    out[(size_t)i * 5 + d] = dinv[i] * (acc0 + acc1);
}

// ---------- final: out = log_softmax(out + b), 5 classes, in-place ----------
__global__ void k_logsoftmax5(float* __restrict__ io, const float* __restrict__ b, int N) {
    int i = blockIdx.x * blockDim.x + threadIdx.x;
    if (i >= N) return;
    float v[5];
    #pragma unroll
    for (int j = 0; j < 5; ++j) v[j] = io[(long long)i * 5 + j] + b[j];
    float m = v[0];
    #pragma unroll
    for (int j = 1; j < 5; ++j) m = fmaxf(m, v[j]);
    float s = 0.0f;
    #pragma unroll
    for (int j = 0; j < 5; ++j) s += expf(v[j] - m);
    float ls = m + logf(s);
    #pragma unroll
    for (int j = 0; j < 5; ++j) io[(long long)i * 5 + j] = v[j] - ls;
}

extern "C" void kernel_launch(void* const* d_in, const int* in_sizes, int n_in,
                              void* d_out, int out_size, void* d_ws, size_t ws_size,
                              hipStream_t stream) {
    const float* x  = (const float*)d_in[0];
    const int*   ei = (const int*)d_in[1];   // [2, E] int32
    const float* W1 = (const float*)d_in[2];
    const float* b1 = (const float*)d_in[3];
    const float* W2 = (const float*)d_in[4];
    const float* b2 = (const float*)d_in[5];
    const float* W3 = (const float*)d_in[6];
    const float* b3 = (const float*)d_in[7];
    const float* W4 = (const float*)d_in[8];
    const float* b4 = (const float*)d_in[9];

    const int N = in_sizes[0];        // 100000
    const int E = in_sizes[1] / 2;    // 3200000
    float* out = (float*)d_out;
    const int* src = ei;
    const int* dst = ei + E;
    (void)n_in; (void)out_size; (void)ws_size;

    const int NB = (N + 255) >> 8;    // 391 buckets

    // ---- workspace layout (256B aligned; total ~65.2MB, same as proven footprint) ----
    auto align_up = [](size_t v) { return (v + 255) & ~(size_t)255; };
    char* p = (char*)d_ws;
    int*      rowptr = (int*)p;      p += align_up(sizeof(int) * (size_t)(N + 1));
    float*    dinv   = (float*)p;    p += align_up(sizeof(float) * (size_t)N);
    int*      bcnt   = (int*)p;      p += align_up(sizeof(int) * (MAXNB + 1));
    int*      bbase  = (int*)p;      p += align_up(sizeof(int) * (MAXNB + 1));
    int*      bcur   = (int*)p;      p += align_up(sizeof(int) * (MAXNB + 1));
    float*    g0     = (float*)p;    p += align_up(sizeof(float) * (size_t)N);
    int*      col    = (int*)p;      p += align_up(sizeof(int) * (size_t)E);
    unsigned* g2     = (unsigned*)p; p += align_up(sizeof(unsigned) * (size_t)N * 32);
    float*    agg2   = (float*)p;    p += align_up(sizeof(float) * (size_t)N * 64);
    char*     X      = p;            p += align_up(sizeof(int) * (size_t)E);
    // region X: ebuf (build) -> agg1 (N*16 f32 @0) + g1 (N*8 u32 @ +N*16*4)
    int*      ebuf   = (int*)X;
    float*    agg1   = (float*)X;
    unsigned* g1     = (unsigned*)(X + align_up(sizeof(float) * (size_t)N * 16));
    float*    zs     = (float*)g2;   // g2 dead after k_aggh64; zs = N*5 f32

    // ---- CSR build (bucketed) ----
    constexpr int ITER = 32;
    const int gBkt = nblk(E, BLK * ITER);
    k_zero_i32<<<nblk(NB), BLK, 0, stream>>>(bcnt, NB);
    k_bucket_hist<ITER><<<gBkt, BLK, 0, stream>>>(dst, bcnt, E, NB);
    k_bucket_scan<<<1, 512, 0, stream>>>(bcnt, bbase, bcur, NB);
    k_bin<ITER><<<gBkt, BLK, 0, stream>>>(src, dst, bcur, ebuf, E, NB);
    k_build<<<NB, 512, 0, stream>>>(bbase, ebuf, rowptr, dinv, col, N);

    // ---- L1: g0 = dinv*x; fused agg + 1->16 -> g1 (half2, scaled) ----
    k_scale_x<<<nblk(N), BLK, 0, stream>>>(x, dinv, g0, N);
    k_agg1_t16<<<nblk(N), BLK, 0, stream>>>(col, rowptr, dinv, g0, W1, b1, g1, N);

    // ---- L2: agg16 -> agg1 f32; transform 16->64 -> g2 (half2, scaled) ----
    k_aggh16<<<nblk(N, 32), 256, 0, stream>>>(col, rowptr, dinv, g1, agg1, N);
    k_t2<<<nblk((long long)N * 32), 256, 0, stream>>>(agg1, W2, b2, dinv, g2, N);

    // ---- L3: agg64 -> agg2 f32; fused 64->64->5 -> zs f32 (scaled) ----
    k_aggh64<<<nblk(N, 16), 256, 0, stream>>>(col, rowptr, dinv, (const uint2*)g2, agg2, N);
    k_t34<<<nblk(N, 32), 256, 0, stream>>>(agg2, W3, b3, W4, dinv, zs, N);

    // ---- L4: agg5 -> out; logsoftmax ----
    k_agg5<<<nblk(N, 64), 320, 0, stream>>>(col, rowptr, dinv, zs, out, N);
    k_logsoftmax5<<<nblk(N), BLK, 0, stream>>>(out, b4, N);
}

// Round 7
// 328.423 us; speedup vs baseline: 2.4646x; 1.1025x over previous
//
#include <hip/hip_runtime.h>
#include <hip/hip_fp16.h>

constexpr int BLK = 256;
static inline int nblk(long long total, int blk = BLK) { return (int)((total + blk - 1) / blk); }

constexpr int MAXNB = 400;
constexpr int CAP = 12288;  // LDS edge capacity in k_build (mean 8184, sigma ~90)

__device__ inline float2 h2f2(unsigned u) {
    __half2 h = *reinterpret_cast<__half2*>(&u);
    return __half22float2(h);
}
__device__ inline unsigned f2h2(float a, float b) {
    __half2 h = __floats2half2_rn(a, b);
    return *reinterpret_cast<unsigned*>(&h);
}

// ---------- utility ----------
__global__ void k_zero_i32(int* __restrict__ p, int n) {
    int i = blockIdx.x * blockDim.x + threadIdx.x;
    if (i < n) p[i] = 0;
}

// ---------- Pass A: bucket histogram ----------
template<int ITER>
__global__ void k_bucket_hist(const int* __restrict__ dst, int* __restrict__ bcnt, int E, int NB) {
    __shared__ int h[MAXNB];
    for (int t = threadIdx.x; t < NB; t += blockDim.x) h[t] = 0;
    __syncthreads();
    long long b0 = (long long)blockIdx.x * blockDim.x * ITER;
    for (int k = 0; k < ITER; ++k) {
        long long e = b0 + (long long)k * blockDim.x + threadIdx.x;
        if (e < E) atomicAdd(&h[dst[e] >> 8], 1);
    }
    __syncthreads();
    for (int t = threadIdx.x; t < NB; t += blockDim.x)
        if (h[t]) atomicAdd(&bcnt[t], h[t]);
}

// ---------- bucket exclusive scan (1 block, NB <= 512); also inits bucket cursors ----------
__global__ void k_bucket_scan(const int* __restrict__ bcnt, int* __restrict__ bbase,
                              int* __restrict__ bcur, int NB) {
    __shared__ int s[512];
    int i = threadIdx.x;
    int v = (i < NB) ? bcnt[i] : 0;
    s[i] = v;
    __syncthreads();
    for (int off = 1; off < 512; off <<= 1) {
        int t = (i >= off) ? s[i - off] : 0;
        __syncthreads();
        s[i] += t;
        __syncthreads();
    }
    int ex = s[i] - v;  // exclusive
    if (i < NB) { bbase[i] = ex; bcur[i] = ex; }
    if (i == NB - 1) bbase[NB] = ex + v;  // = E
}

// ---------- Pass B: bin packed edges into bucket regions (dst cached in LDS) ----------
template<int ITER>
__global__ void k_bin(const int* __restrict__ src, const int* __restrict__ dst,
                      int* __restrict__ bcur, int* __restrict__ ebuf, int E, int NB) {
    __shared__ int cnt[MAXNB];
    __shared__ int basei[MAXNB];
    __shared__ int dstL[BLK * ITER];   // 32 KB
    for (int t = threadIdx.x; t < NB; t += blockDim.x) cnt[t] = 0;
    __syncthreads();
    long long b0 = (long long)blockIdx.x * blockDim.x * ITER;
    for (int k = 0; k < ITER; ++k) {   // sweep 1: count + cache dst
        long long e = b0 + (long long)k * blockDim.x + threadIdx.x;
        if (e < E) {
            int d = dst[e];
            dstL[k * BLK + threadIdx.x] = d;
            atomicAdd(&cnt[d >> 8], 1);
        }
    }
    __syncthreads();
    for (int t = threadIdx.x; t < NB; t += blockDim.x) {  // reserve runs
        int c = cnt[t];
        basei[t] = c ? atomicAdd(&bcur[t], c) : 0;
    }
    __syncthreads();
    for (int t = threadIdx.x; t < NB; t += blockDim.x) cnt[t] = 0;  // reuse as cursor
    __syncthreads();
    for (int k = 0; k < ITER; ++k) {   // sweep 2: write (dst from LDS)
        long long e = b0 + (long long)k * blockDim.x + threadIdx.x;
        if (e < E) {
            int d = dstL[k * BLK + threadIdx.x];
            int s = src[e];
            int b = d >> 8;
            int pos = basei[b] + atomicAdd(&cnt[b], 1);
            ebuf[pos] = ((d & 255) << 17) | s;
        }
    }
}

// ---------- Pass C: per-bucket fused hist+scan -> rowptr, dinv, g0, col ----------
__global__ __launch_bounds__(512) void k_build(const int* __restrict__ bbase,
                                               const int* __restrict__ ebuf,
                                               int* __restrict__ rowptr, float* __restrict__ dinv,
                                               const float* __restrict__ x, float* __restrict__ g0,
                                               int* __restrict__ col, int N) {
    __shared__ int eLds[CAP];
    __shared__ int cnt[256];
    __shared__ int scn[256];
    int b = blockIdx.x;
    int base = bbase[b];
    int size = bbase[b + 1] - base;
    for (int t = threadIdx.x; t < 256; t += blockDim.x) cnt[t] = 0;
    for (int k = threadIdx.x; k < size && k < CAP; k += blockDim.x) eLds[k] = ebuf[base + k];
    __syncthreads();
    for (int k = threadIdx.x; k < size; k += blockDim.x) {   // hist
        int pv = (k < CAP) ? eLds[k] : ebuf[base + k];
        atomicAdd(&cnt[pv >> 17], 1);
    }
    __syncthreads();
    if (threadIdx.x < 256) scn[threadIdx.x] = cnt[threadIdx.x];
    __syncthreads();
    for (int off = 1; off < 256; off <<= 1) {   // inclusive scan
        int t = (threadIdx.x < 256 && threadIdx.x >= off) ? scn[threadIdx.x - off] : 0;
        __syncthreads();
        if (threadIdx.x < 256) scn[threadIdx.x] += t;
        __syncthreads();
    }
    int node0 = b << 8;
    if (threadIdx.x < 256) {
        int node = node0 + threadIdx.x;
        int ex = scn[threadIdx.x] - cnt[threadIdx.x];  // exclusive
        if (node <= N) rowptr[node] = base + ex;       // node==N -> rowptr[N]=E
        if (node < N) {
            float dv = rsqrtf((float)(cnt[threadIdx.x] + 1)); // +1 self-loop
            dinv[node] = dv;
            g0[node] = dv * x[node];                    // fused pre-scale of layer-1 input
        }
        cnt[threadIdx.x] = ex;                          // repurpose as cursor
    }
    __syncthreads();
    for (int k = threadIdx.x; k < size; k += blockDim.x) {   // fill
        int pv = (k < CAP) ? eLds[k] : ebuf[base + k];
        int pos = atomicAdd(&cnt[pv >> 17], 1);
        col[base + pos] = pv & 0x1FFFF;
    }
}

// ---------- fused: L1 aggregate (D=1, pre-scaled) + 1->16 + ReLU -> packed half2, scaled ----------
__global__ void k_agg1_t16(const int* __restrict__ col, const int* __restrict__ rowptr,
                           const float* __restrict__ dinv, const float* __restrict__ g0,
                           const float* __restrict__ W1, const float* __restrict__ b1,
                           unsigned* __restrict__ g1, int N) {
    __shared__ float sW[16], sb[16];
    if (threadIdx.x < 16) { sW[threadIdx.x] = W1[threadIdx.x]; sb[threadIdx.x] = b1[threadIdx.x]; }
    __syncthreads();
    int i = blockIdx.x * blockDim.x + threadIdx.x;
    if (i >= N) return;
    int beg = rowptr[i], end = rowptr[i + 1];
    float acc0 = g0[i], acc1 = 0.0f;
    int e = beg;
    for (; e + 3 < end; e += 4) {
        int s0 = col[e], s1 = col[e + 1], s2 = col[e + 2], s3 = col[e + 3];
        acc0 += g0[s0]; acc1 += g0[s1]; acc0 += g0[s2]; acc1 += g0[s3];
    }
    for (; e < end; ++e) acc0 += g0[col[e]];
    float di = dinv[i];
    float a = di * (acc0 + acc1);
    unsigned up[8];
    #pragma unroll
    for (int q = 0; q < 8; ++q) {
        float r0 = fmaxf(fmaf(a, sW[2 * q + 0], sb[2 * q + 0]), 0.0f) * di;
        float r1 = fmaxf(fmaf(a, sW[2 * q + 1], sb[2 * q + 1]), 0.0f) * di;
        up[q] = f2h2(r0, r1);
    }
    uint4* op = (uint4*)(g1 + (size_t)i * 8);
    op[0] = make_uint4(up[0], up[1], up[2], up[3]);
    op[1] = make_uint4(up[4], up[5], up[6], up[7]);
}

// ---------- agg D=16 from packed half2: 4 lanes/node, uint2 loads, 4-edge unroll ----------
__global__ void k_aggh16(const int* __restrict__ col, const int* __restrict__ rowptr,
                         const float* __restrict__ dinv, const uint2* __restrict__ g1,
                         float* __restrict__ agg1, int N) {
    int l = threadIdx.x & 3, g = threadIdx.x >> 2;   // 4 lanes/node, 64 nodes/block
    int i = blockIdx.x * 64 + g;
    if (i >= N) return;
    int beg = rowptr[i], end = rowptr[i + 1];
    uint2 us = g1[(size_t)i * 4 + l];                // self term (dims 4l..4l+3)
    float2 aA = h2f2(us.x), aB = h2f2(us.y);
    float2 bA = {0.0f, 0.0f}, bB = {0.0f, 0.0f};
    int e = beg;
    for (; e + 3 < end; e += 4) {
        int s0 = col[e], s1 = col[e + 1], s2 = col[e + 2], s3 = col[e + 3];
        uint2 u0 = g1[(size_t)s0 * 4 + l];
        uint2 u1 = g1[(size_t)s1 * 4 + l];
        uint2 u2 = g1[(size_t)s2 * 4 + l];
        uint2 u3 = g1[(size_t)s3 * 4 + l];
        float2 f;
        f = h2f2(u0.x); aA.x += f.x; aA.y += f.y;
        f = h2f2(u0.y); aB.x += f.x; aB.y += f.y;
        f = h2f2(u1.x); bA.x += f.x; bA.y += f.y;
        f = h2f2(u1.y); bB.x += f.x; bB.y += f.y;
        f = h2f2(u2.x); aA.x += f.x; aA.y += f.y;
        f = h2f2(u2.y); aB.x += f.x; aB.y += f.y;
        f = h2f2(u3.x); bA.x += f.x; bA.y += f.y;
        f = h2f2(u3.y); bB.x += f.x; bB.y += f.y;
    }
    for (; e < end; ++e) {
        uint2 u = g1[(size_t)col[e] * 4 + l];
        float2 f;
        f = h2f2(u.x); aA.x += f.x; aA.y += f.y;
        f = h2f2(u.y); aB.x += f.x; aB.y += f.y;
    }
    float di = dinv[i];
    float4 o = make_float4(di * (aA.x + bA.x), di * (aA.y + bA.y),
                           di * (aB.x + bB.x), di * (aB.y + bB.y));
    *(float4*)&agg1[(size_t)i * 16 + l * 4] = o;
}

// ---------- transform 16->64 (ReLU), output packed half2 scaled by dinv ----------
__global__ void k_t2(const float* __restrict__ agg1, const float* __restrict__ W2,
                     const float* __restrict__ b2, const float* __restrict__ dinv,
                     unsigned* __restrict__ g2, int N) {
    __shared__ float sW[16 * 64];
    __shared__ float sb[64];
    for (int k = threadIdx.x; k < 16 * 64; k += blockDim.x) sW[k] = W2[k];
    if (threadIdx.x < 64) sb[threadIdx.x] = b2[threadIdx.x];
    __syncthreads();
    long long gid = (long long)blockIdx.x * blockDim.x + threadIdx.x;
    if (gid >= (long long)N * 32) return;
    int i = (int)(gid >> 5), jj = (int)(gid & 31);
    int j0 = 2 * jj, j1 = 2 * jj + 1;
    const float* row = agg1 + (size_t)i * 16;
    float a0 = sb[j0], a1 = sb[j1];
    #pragma unroll
    for (int d = 0; d < 16; ++d) {
        float r = row[d];
        a0 = fmaf(r, sW[d * 64 + j0], a0);
        a1 = fmaf(r, sW[d * 64 + j1], a1);
    }
    float di = dinv[i];
    g2[gid] = f2h2(fmaxf(a0, 0.0f) * di, fmaxf(a1, 0.0f) * di);
}

// ---------- agg D=64: 8 lanes/node, uint4 loads, 4-edge unroll ----------
__global__ void k_aggh64(const int* __restrict__ col, const int* __restrict__ rowptr,
                         const float* __restrict__ dinv, const uint4* __restrict__ g2,
                         float* __restrict__ agg2, int N) {
    int l = threadIdx.x & 7, g = threadIdx.x >> 3;   // 8 lanes/node, 32 nodes/block
    int i = blockIdx.x * 32 + g;
    if (i >= N) return;
    int beg = rowptr[i], end = rowptr[i + 1];
    uint4 us = g2[(size_t)i * 8 + l];                // self term (dims 8l..8l+7)
    float2 a0 = h2f2(us.x), a1 = h2f2(us.y), a2 = h2f2(us.z), a3 = h2f2(us.w);
    float2 b0 = {0, 0}, b1 = {0, 0}, b2 = {0, 0}, b3 = {0, 0};
    int e = beg;
    for (; e + 3 < end; e += 4) {
        int s0 = col[e], s1 = col[e + 1], s2 = col[e + 2], s3 = col[e + 3];
        uint4 u0 = g2[(size_t)s0 * 8 + l];
        uint4 u1 = g2[(size_t)s1 * 8 + l];
        uint4 u2 = g2[(size_t)s2 * 8 + l];
        uint4 u3 = g2[(size_t)s3 * 8 + l];
        float2 f;
        f = h2f2(u0.x); a0.x += f.x; a0.y += f.y;
        f = h2f2(u0.y); a1.x += f.x; a1.y += f.y;
        f = h2f2(u0.z); a2.x += f.x; a2.y += f.y;
        f = h2f2(u0.w); a3.x += f.x; a3.y += f.y;
        f = h2f2(u1.x); b0.x += f.x; b0.y += f.y;
        f = h2f2(u1.y); b1.x += f.x; b1.y += f.y;
        f = h2f2(u1.z); b2.x += f.x; b2.y += f.y;
        f = h2f2(u1.w); b3.x += f.x; b3.y += f.y;
        f = h2f2(u2.x); a0.x += f.x; a0.y += f.y;
        f = h2f2(u2.y); a1.x += f.x; a1.y += f.y;
        f = h2f2(u2.z); a2.x += f.x; a2.y += f.y;
        f = h2f2(u2.w); a3.x += f.x; a3.y += f.y;
        f = h2f2(u3.x); b0.x += f.x; b0.y += f.y;
        f = h2f2(u3.y); b1.x += f.x; b1.y += f.y;
        f = h2f2(u3.z); b2.x += f.x; b2.y += f.y;
        f = h2f2(u3.w); b3.x += f.x; b3.y += f.y;
    }
    for (; e < end; ++e) {
        uint4 u = g2[(size_t)col[e] * 8 + l];
        float2 f;
        f = h2f2(u.x); a0.x += f.x; a0.y += f.y;
        f = h2f2(u.y); a1.x += f.x; a1.y += f.y;
        f = h2f2(u.z); a2.x += f.x; a2.y += f.y;
        f = h2f2(u.w); a3.x += f.x; a3.y += f.y;
    }
    float di = dinv[i];
    float4 o0 = make_float4(di * (a0.x + b0.x), di * (a0.y + b0.y),
                            di * (a1.x + b1.x), di * (a1.y + b1.y));
    float4 o1 = make_float4(di * (a2.x + b2.x), di * (a2.y + b2.y),
                            di * (a3.x + b3.x), di * (a3.y + b3.y));
    *(float4*)&agg2[(size_t)i * 64 + l * 8] = o0;
    *(float4*)&agg2[(size_t)i * 64 + l * 8 + 4] = o1;
}

// ---------- fused transforms: h3 = relu(agg2 W3 + b3); zs = dinv * (h3 W4) ----------
__global__ __launch_bounds__(256) void k_t34(const float* __restrict__ agg2,
                                             const float* __restrict__ W3, const float* __restrict__ b3,
                                             const float* __restrict__ W4, const float* __restrict__ dinv,
                                             float* __restrict__ zs, int N) {
    __shared__ float sW3[64 * 64];
    __shared__ float sb3[64];
    __shared__ float sW4[64 * 5];
    __shared__ float row[4][64];
    __shared__ float h3[4][64];
    for (int k = threadIdx.x; k < 64 * 64; k += 256) sW3[k] = W3[k];
    if (threadIdx.x < 64) sb3[threadIdx.x] = b3[threadIdx.x];
    for (int k = threadIdx.x; k < 320; k += 256) sW4[k] = W4[k];
    __syncthreads();
    int g = threadIdx.x >> 6, j = threadIdx.x & 63;
    for (int r = 0; r < 8; ++r) {
        int i = blockIdx.x * 32 + r * 4 + g;
        bool ok = i < N;
        if (ok) row[g][j] = agg2[(size_t)i * 64 + j];
        __syncthreads();
        if (ok) {
            float a = sb3[j];
            #pragma unroll
            for (int d = 0; d < 64; ++d) a = fmaf(row[g][d], sW3[d * 64 + j], a);
            h3[g][j] = fmaxf(a, 0.0f);
        }
        __syncthreads();
        if (ok && j < 5) {
            float z = 0.0f;
            #pragma unroll
            for (int d = 0; d < 64; ++d) z = fmaf(h3[g][d], sW4[d * 5 + j], z);
            zs[(size_t)i * 5 + j] = dinv[i] * z;
        }
        __syncthreads();
    }
}

// ---------- agg D=5 f32 (pre-scaled) -> d_out ----------
__global__ void k_agg5(const int* __restrict__ col, const int* __restrict__ rowptr,
                       const float* __restrict__ dinv, const float* __restrict__ zs,
                       float* __restrict__ out, int N) {
    int g = threadIdx.x / 5, d = threadIdx.x % 5;   // 64 nodes per 320-block
    int i = blockIdx.x * 64 + g;
    if (i >= N || threadIdx.x >= 320) return;
    int beg = rowptr[i], end = rowptr[i + 1];
    float acc0 = zs[(size_t)i * 5 + d], acc1 = 0.0f;
    int e = beg;
    for (; e + 1 < end; e += 2) {
        int s0 = col[e], s1 = col[e + 1];
        acc0 += zs[(size_t)s0 * 5 + d];
        acc1 += zs[(size_t)s1 * 5 + d];
    }
    if (e < end) acc0 += zs[(size_t)col[e] * 5 + d];
    out[(size_t)i * 5 + d] = dinv[i] * (acc0 + acc1);
}

// ---------- final: out = log_softmax(out + b), 5 classes, in-place ----------
__global__ void k_logsoftmax5(float* __restrict__ io, const float* __restrict__ b, int N) {
    int i = blockIdx.x * blockDim.x + threadIdx.x;
    if (i >= N) return;
    float v[5];
    #pragma unroll
    for (int j = 0; j < 5; ++j) v[j] = io[(long long)i * 5 + j] + b[j];
    float m = v[0];
    #pragma unroll
    for (int j = 1; j < 5; ++j) m = fmaxf(m, v[j]);
    float s = 0.0f;
    #pragma unroll
    for (int j = 0; j < 5; ++j) s += expf(v[j] - m);
    float ls = m + logf(s);
    #pragma unroll
    for (int j = 0; j < 5; ++j) io[(long long)i * 5 + j] = v[j] - ls;
}

extern "C" void kernel_launch(void* const* d_in, const int* in_sizes, int n_in,
                              void* d_out, int out_size, void* d_ws, size_t ws_size,
                              hipStream_t stream) {
    const float* x  = (const float*)d_in[0];
    const int*   ei = (const int*)d_in[1];   // [2, E] int32
    const float* W1 = (const float*)d_in[2];
    const float* b1 = (const float*)d_in[3];
    const float* W2 = (const float*)d_in[4];
    const float* b2 = (const float*)d_in[5];
    const float* W3 = (const float*)d_in[6];
    const float* b3 = (const float*)d_in[7];
    const float* W4 = (const float*)d_in[8];
    const float* b4 = (const float*)d_in[9];

    const int N = in_sizes[0];        // 100000
    const int E = in_sizes[1] / 2;    // 3200000
    float* out = (float*)d_out;
    const int* src = ei;
    const int* dst = ei + E;
    (void)n_in; (void)out_size; (void)ws_size;

    const int NB = (N + 255) >> 8;    // 391 buckets

    // ---- workspace layout (256B aligned; ~65.2MB, same proven footprint) ----
    auto align_up = [](size_t v) { return (v + 255) & ~(size_t)255; };
    char* p = (char*)d_ws;
    int*      rowptr = (int*)p;      p += align_up(sizeof(int) * (size_t)(N + 1));
    float*    dinv   = (float*)p;    p += align_up(sizeof(float) * (size_t)N);
    int*      bcnt   = (int*)p;      p += align_up(sizeof(int) * (MAXNB + 1));
    int*      bbase  = (int*)p;      p += align_up(sizeof(int) * (MAXNB + 1));
    int*      bcur   = (int*)p;      p += align_up(sizeof(int) * (MAXNB + 1));
    float*    g0     = (float*)p;    p += align_up(sizeof(float) * (size_t)N);
    int*      col    = (int*)p;      p += align_up(sizeof(int) * (size_t)E);
    unsigned* g2     = (unsigned*)p; p += align_up(sizeof(unsigned) * (size_t)N * 32);
    float*    agg2   = (float*)p;    p += align_up(sizeof(float) * (size_t)N * 64);
    char*     X      = p;            p += align_up(sizeof(int) * (size_t)E);
    // region X: ebuf (build) -> agg1 (N*16 f32 @0) + g1 (N*8 u32 @ +N*16*4)
    int*      ebuf   = (int*)X;
    float*    agg1   = (float*)X;
    unsigned* g1     = (unsigned*)(X + align_up(sizeof(float) * (size_t)N * 16));
    float*    zs     = (float*)g2;   // g2 dead after k_aggh64; zs = N*5 f32

    // ---- CSR build (bucketed) ----
    constexpr int ITER = 32;
    const int gBkt = nblk(E, BLK * ITER);
    k_zero_i32<<<nblk(NB), BLK, 0, stream>>>(bcnt, NB);
    k_bucket_hist<ITER><<<gBkt, BLK, 0, stream>>>(dst, bcnt, E, NB);
    k_bucket_scan<<<1, 512, 0, stream>>>(bcnt, bbase, bcur, NB);
    k_bin<ITER><<<gBkt, BLK, 0, stream>>>(src, dst, bcur, ebuf, E, NB);
    k_build<<<NB, 512, 0, stream>>>(bbase, ebuf, rowptr, dinv, x, g0, col, N);

    // ---- L1: fused agg + 1->16 -> g1 (half2, scaled) ----
    k_agg1_t16<<<nblk(N), BLK, 0, stream>>>(col, rowptr, dinv, g0, W1, b1, g1, N);

    // ---- L2: agg16 -> agg1 f32; transform 16->64 -> g2 (half2, scaled) ----
    k_aggh16<<<nblk(N, 64), 256, 0, stream>>>(col, rowptr, dinv, (const uint2*)g1, agg1, N);
    k_t2<<<nblk((long long)N * 32), 256, 0, stream>>>(agg1, W2, b2, dinv, g2, N);

    // ---- L3: agg64 -> agg2 f32; fused 64->64->5 -> zs f32 (scaled) ----
    k_aggh64<<<nblk(N, 32), 256, 0, stream>>>(col, rowptr, dinv, (const uint4*)g2, agg2, N);
    k_t34<<<nblk(N, 32), 256, 0, stream>>>(agg2, W3, b3, W4, dinv, zs, N);

    // ---- L4: agg5 -> out; logsoftmax ----
    k_agg5<<<nblk(N, 64), 320, 0, stream>>>(col, rowptr, dinv, zs, out, N);
    k_logsoftmax5<<<nblk(N), BLK, 0, stream>>>(out, b4, N);
}

// Round 8
// 276.544 us; speedup vs baseline: 2.9270x; 1.1876x over previous
//
#include <hip/hip_runtime.h>
#include <hip/hip_fp16.h>

constexpr int BLK = 256;
static inline int nblk(long long total, int blk = BLK) { return (int)((total + blk - 1) / blk); }

constexpr int MAXNB = 400;
constexpr int CAP = 12288;  // LDS edge capacity in k_build (mean 8184, sigma ~90)

__device__ inline float2 h2f2(unsigned u) {
    __half2 h = *reinterpret_cast<__half2*>(&u);
    return __half22float2(h);
}
__device__ inline unsigned f2h2(float a, float b) {
    __half2 h = __floats2half2_rn(a, b);
    return *reinterpret_cast<unsigned*>(&h);
}

// ---------- utility ----------
__global__ void k_zero_i32(int* __restrict__ p, int n) {
    int i = blockIdx.x * blockDim.x + threadIdx.x;
    if (i < n) p[i] = 0;
}

// ---------- Pass A: bucket histogram ----------
template<int ITER>
__global__ void k_bucket_hist(const int* __restrict__ dst, int* __restrict__ bcnt, int E, int NB) {
    __shared__ int h[MAXNB];
    for (int t = threadIdx.x; t < NB; t += blockDim.x) h[t] = 0;
    __syncthreads();
    long long b0 = (long long)blockIdx.x * blockDim.x * ITER;
    for (int k = 0; k < ITER; ++k) {
        long long e = b0 + (long long)k * blockDim.x + threadIdx.x;
        if (e < E) atomicAdd(&h[dst[e] >> 8], 1);
    }
    __syncthreads();
    for (int t = threadIdx.x; t < NB; t += blockDim.x)
        if (h[t]) atomicAdd(&bcnt[t], h[t]);
}

// ---------- bucket exclusive scan (1 block, NB <= 512); also inits bucket cursors ----------
__global__ void k_bucket_scan(const int* __restrict__ bcnt, int* __restrict__ bbase,
                              int* __restrict__ bcur, int NB) {
    __shared__ int s[512];
    int i = threadIdx.x;
    int v = (i < NB) ? bcnt[i] : 0;
    s[i] = v;
    __syncthreads();
    for (int off = 1; off < 512; off <<= 1) {
        int t = (i >= off) ? s[i - off] : 0;
        __syncthreads();
        s[i] += t;
        __syncthreads();
    }
    int ex = s[i] - v;  // exclusive
    if (i < NB) { bbase[i] = ex; bcur[i] = ex; }
    if (i == NB - 1) bbase[NB] = ex + v;  // = E
}

// ---------- Pass B: bin packed edges into bucket regions (dst cached in LDS) ----------
template<int ITER>
__global__ void k_bin(const int* __restrict__ src, const int* __restrict__ dst,
                      int* __restrict__ bcur, int* __restrict__ ebuf, int E, int NB) {
    __shared__ int cnt[MAXNB];
    __shared__ int basei[MAXNB];
    __shared__ int dstL[BLK * ITER];   // 32 KB
    for (int t = threadIdx.x; t < NB; t += blockDim.x) cnt[t] = 0;
    __syncthreads();
    long long b0 = (long long)blockIdx.x * blockDim.x * ITER;
    for (int k = 0; k < ITER; ++k) {   // sweep 1: count + cache dst
        long long e = b0 + (long long)k * blockDim.x + threadIdx.x;
        if (e < E) {
            int d = dst[e];
            dstL[k * BLK + threadIdx.x] = d;
            atomicAdd(&cnt[d >> 8], 1);
        }
    }
    __syncthreads();
    for (int t = threadIdx.x; t < NB; t += blockDim.x) {  // reserve runs
        int c = cnt[t];
        basei[t] = c ? atomicAdd(&bcur[t], c) : 0;
    }
    __syncthreads();
    for (int t = threadIdx.x; t < NB; t += blockDim.x) cnt[t] = 0;  // reuse as cursor
    __syncthreads();
    for (int k = 0; k < ITER; ++k) {   // sweep 2: write (dst from LDS)
        long long e = b0 + (long long)k * blockDim.x + threadIdx.x;
        if (e < E) {
            int d = dstL[k * BLK + threadIdx.x];
            int s = src[e];
            int b = d >> 8;
            int pos = basei[b] + atomicAdd(&cnt[b], 1);
            ebuf[pos] = ((d & 255) << 17) | s;
        }
    }
}

// ---------- Pass C: per-bucket fused hist+scan -> rowptr, dinv, g0, col ----------
__global__ __launch_bounds__(512) void k_build(const int* __restrict__ bbase,
                                               const int* __restrict__ ebuf,
                                               int* __restrict__ rowptr, float* __restrict__ dinv,
                                               const float* __restrict__ x, float* __restrict__ g0,
                                               int* __restrict__ col, int N) {
    __shared__ int eLds[CAP];
    __shared__ int cnt[256];
    __shared__ int scn[256];
    int b = blockIdx.x;
    int base = bbase[b];
    int size = bbase[b + 1] - base;
    for (int t = threadIdx.x; t < 256; t += blockDim.x) cnt[t] = 0;
    for (int k = threadIdx.x; k < size && k < CAP; k += blockDim.x) eLds[k] = ebuf[base + k];
    __syncthreads();
    for (int k = threadIdx.x; k < size; k += blockDim.x) {   // hist
        int pv = (k < CAP) ? eLds[k] : ebuf[base + k];
        atomicAdd(&cnt[pv >> 17], 1);
    }
    __syncthreads();
    if (threadIdx.x < 256) scn[threadIdx.x] = cnt[threadIdx.x];
    __syncthreads();
    for (int off = 1; off < 256; off <<= 1) {   // inclusive scan
        int t = (threadIdx.x < 256 && threadIdx.x >= off) ? scn[threadIdx.x - off] : 0;
        __syncthreads();
        if (threadIdx.x < 256) scn[threadIdx.x] += t;
        __syncthreads();
    }
    int node0 = b << 8;
    if (threadIdx.x < 256) {
        int node = node0 + threadIdx.x;
        int ex = scn[threadIdx.x] - cnt[threadIdx.x];  // exclusive
        if (node <= N) rowptr[node] = base + ex;       // node==N -> rowptr[N]=E
        if (node < N) {
            float dv = rsqrtf((float)(cnt[threadIdx.x] + 1)); // +1 self-loop
            dinv[node] = dv;
            g0[node] = dv * x[node];                    // fused pre-scale of layer-1 input
        }
        cnt[threadIdx.x] = ex;                          // repurpose as cursor
    }
    __syncthreads();
    for (int k = threadIdx.x; k < size; k += blockDim.x) {   // fill
        int pv = (k < CAP) ? eLds[k] : ebuf[base + k];
        int pos = atomicAdd(&cnt[pv >> 17], 1);
        col[base + pos] = pv & 0x1FFFF;
    }
}

// ---------- fused: L1 aggregate (D=1, pre-scaled) + 1->16 + ReLU -> packed half2, scaled ----------
__global__ void k_agg1_t16(const int* __restrict__ col, const int* __restrict__ rowptr,
                           const float* __restrict__ dinv, const float* __restrict__ g0,
                           const float* __restrict__ W1, const float* __restrict__ b1,
                           unsigned* __restrict__ g1, int N) {
    __shared__ float sW[16], sb[16];
    if (threadIdx.x < 16) { sW[threadIdx.x] = W1[threadIdx.x]; sb[threadIdx.x] = b1[threadIdx.x]; }
    __syncthreads();
    int i = blockIdx.x * blockDim.x + threadIdx.x;
    if (i >= N) return;
    int beg = rowptr[i], end = rowptr[i + 1];
    float acc0 = g0[i], acc1 = 0.0f;
    int e = beg;
    for (; e + 3 < end; e += 4) {
        int s0 = col[e], s1 = col[e + 1], s2 = col[e + 2], s3 = col[e + 3];
        acc0 += g0[s0]; acc1 += g0[s1]; acc0 += g0[s2]; acc1 += g0[s3];
    }
    for (; e < end; ++e) acc0 += g0[col[e]];
    float di = dinv[i];
    float a = di * (acc0 + acc1);
    unsigned up[8];
    #pragma unroll
    for (int q = 0; q < 8; ++q) {
        float r0 = fmaxf(fmaf(a, sW[2 * q + 0], sb[2 * q + 0]), 0.0f) * di;
        float r1 = fmaxf(fmaf(a, sW[2 * q + 1], sb[2 * q + 1]), 0.0f) * di;
        up[q] = f2h2(r0, r1);
    }
    uint4* op = (uint4*)(g1 + (size_t)i * 8);
    op[0] = make_uint4(up[0], up[1], up[2], up[3]);
    op[1] = make_uint4(up[4], up[5], up[6], up[7]);
}

// ---------- agg D=16 from packed half2: 4 lanes/node, uint2 loads, 4-edge unroll ----------
__global__ void k_aggh16(const int* __restrict__ col, const int* __restrict__ rowptr,
                         const float* __restrict__ dinv, const uint2* __restrict__ g1,
                         float* __restrict__ agg1, int N) {
    int l = threadIdx.x & 3, g = threadIdx.x >> 2;   // 4 lanes/node, 64 nodes/block
    int i = blockIdx.x * 64 + g;
    if (i >= N) return;
    int beg = rowptr[i], end = rowptr[i + 1];
    uint2 us = g1[(size_t)i * 4 + l];                // self term (dims 4l..4l+3)
    float2 aA = h2f2(us.x), aB = h2f2(us.y);
    float2 bA = {0.0f, 0.0f}, bB = {0.0f, 0.0f};
    int e = beg;
    for (; e + 3 < end; e += 4) {
        int s0 = col[e], s1 = col[e + 1], s2 = col[e + 2], s3 = col[e + 3];
        uint2 u0 = g1[(size_t)s0 * 4 + l];
        uint2 u1 = g1[(size_t)s1 * 4 + l];
        uint2 u2 = g1[(size_t)s2 * 4 + l];
        uint2 u3 = g1[(size_t)s3 * 4 + l];
        float2 f;
        f = h2f2(u0.x); aA.x += f.x; aA.y += f.y;
        f = h2f2(u0.y); aB.x += f.x; aB.y += f.y;
        f = h2f2(u1.x); bA.x += f.x; bA.y += f.y;
        f = h2f2(u1.y); bB.x += f.x; bB.y += f.y;
        f = h2f2(u2.x); aA.x += f.x; aA.y += f.y;
        f = h2f2(u2.y); aB.x += f.x; aB.y += f.y;
        f = h2f2(u3.x); bA.x += f.x; bA.y += f.y;
        f = h2f2(u3.y); bB.x += f.x; bB.y += f.y;
    }
    for (; e < end; ++e) {
        uint2 u = g1[(size_t)col[e] * 4 + l];
        float2 f;
        f = h2f2(u.x); aA.x += f.x; aA.y += f.y;
        f = h2f2(u.y); aB.x += f.x; aB.y += f.y;
    }
    float di = dinv[i];
    float4 o = make_float4(di * (aA.x + bA.x), di * (aA.y + bA.y),
                           di * (aB.x + bB.x), di * (aB.y + bB.y));
    *(float4*)&agg1[(size_t)i * 16 + l * 4] = o;
}

// ---------- transform 16->64 (ReLU) register-tiled: out packed half2 scaled by dinv ----------
// 64-row tile, 256 threads = 16 rowquads x 16 colquads, 4x4 register tile each.
__global__ __launch_bounds__(256) void k_t2v2(const float* __restrict__ agg1,
                                              const float* __restrict__ W2, const float* __restrict__ b2,
                                              const float* __restrict__ dinv,
                                              unsigned* __restrict__ g2, int N) {
    __shared__ alignas(16) float sW[16 * 64];
    __shared__ float sb[64];
    __shared__ float rowsL[64][17];   // odd pad: bank = (row + d) % 32 for stride-17
    int r0 = blockIdx.x * 64;
    for (int k = threadIdx.x; k < 16 * 64; k += 256) sW[k] = W2[k];
    if (threadIdx.x < 64) sb[threadIdx.x] = b2[threadIdx.x];
    for (int idx = threadIdx.x; idx < 64 * 16; idx += 256) {
        int r = idx >> 4, d = idx & 15;
        int gi = r0 + r;
        rowsL[r][d] = (gi < N) ? agg1[(size_t)gi * 16 + d] : 0.0f;
    }
    __syncthreads();
    int rq = threadIdx.x >> 4, cq = threadIdx.x & 15;
    float acc[4][4];
    #pragma unroll
    for (int r = 0; r < 4; ++r)
        #pragma unroll
        for (int c = 0; c < 4; ++c) acc[r][c] = sb[4 * cq + c];
    #pragma unroll
    for (int d = 0; d < 16; ++d) {
        float4 wv = *(const float4*)&sW[d * 64 + 4 * cq];
        #pragma unroll
        for (int r = 0; r < 4; ++r) {
            float rv = rowsL[4 * rq + r][d];
            acc[r][0] = fmaf(rv, wv.x, acc[r][0]);
            acc[r][1] = fmaf(rv, wv.y, acc[r][1]);
            acc[r][2] = fmaf(rv, wv.z, acc[r][2]);
            acc[r][3] = fmaf(rv, wv.w, acc[r][3]);
        }
    }
    #pragma unroll
    for (int r = 0; r < 4; ++r) {
        int gi = r0 + 4 * rq + r;
        if (gi < N) {
            float di = dinv[gi];
            uint2 o;
            o.x = f2h2(fmaxf(acc[r][0], 0.0f) * di, fmaxf(acc[r][1], 0.0f) * di);
            o.y = f2h2(fmaxf(acc[r][2], 0.0f) * di, fmaxf(acc[r][3], 0.0f) * di);
            *(uint2*)&g2[(size_t)gi * 32 + 2 * cq] = o;
        }
    }
}

// ---------- agg D=64: 8 lanes/node, uint4 loads, 4-edge unroll ----------
__global__ void k_aggh64(const int* __restrict__ col, const int* __restrict__ rowptr,
                         const float* __restrict__ dinv, const uint4* __restrict__ g2,
                         float* __restrict__ agg2, int N) {
    int l = threadIdx.x & 7, g = threadIdx.x >> 3;   // 8 lanes/node, 32 nodes/block
    int i = blockIdx.x * 32 + g;
    if (i >= N) return;
    int beg = rowptr[i], end = rowptr[i + 1];
    uint4 us = g2[(size_t)i * 8 + l];                // self term (dims 8l..8l+7)
    float2 a0 = h2f2(us.x), a1 = h2f2(us.y), a2 = h2f2(us.z), a3 = h2f2(us.w);
    float2 b0 = {0, 0}, b1 = {0, 0}, b2 = {0, 0}, b3 = {0, 0};
    int e = beg;
    for (; e + 3 < end; e += 4) {
        int s0 = col[e], s1 = col[e + 1], s2 = col[e + 2], s3 = col[e + 3];
        uint4 u0 = g2[(size_t)s0 * 8 + l];
        uint4 u1 = g2[(size_t)s1 * 8 + l];
        uint4 u2 = g2[(size_t)s2 * 8 + l];
        uint4 u3 = g2[(size_t)s3 * 8 + l];
        float2 f;
        f = h2f2(u0.x); a0.x += f.x; a0.y += f.y;
        f = h2f2(u0.y); a1.x += f.x; a1.y += f.y;
        f = h2f2(u0.z); a2.x += f.x; a2.y += f.y;
        f = h2f2(u0.w); a3.x += f.x; a3.y += f.y;
        f = h2f2(u1.x); b0.x += f.x; b0.y += f.y;
        f = h2f2(u1.y); b1.x += f.x; b1.y += f.y;
        f = h2f2(u1.z); b2.x += f.x; b2.y += f.y;
        f = h2f2(u1.w); b3.x += f.x; b3.y += f.y;
        f = h2f2(u2.x); a0.x += f.x; a0.y += f.y;
        f = h2f2(u2.y); a1.x += f.x; a1.y += f.y;
        f = h2f2(u2.z); a2.x += f.x; a2.y += f.y;
        f = h2f2(u2.w); a3.x += f.x; a3.y += f.y;
        f = h2f2(u3.x); b0.x += f.x; b0.y += f.y;
        f = h2f2(u3.y); b1.x += f.x; b1.y += f.y;
        f = h2f2(u3.z); b2.x += f.x; b2.y += f.y;
        f = h2f2(u3.w); b3.x += f.x; b3.y += f.y;
    }
    for (; e < end; ++e) {
        uint4 u = g2[(size_t)col[e] * 8 + l];
        float2 f;
        f = h2f2(u.x); a0.x += f.x; a0.y += f.y;
        f = h2f2(u.y); a1.x += f.x; a1.y += f.y;
        f = h2f2(u.z); a2.x += f.x; a2.y += f.y;
        f = h2f2(u.w); a3.x += f.x; a3.y += f.y;
    }
    float di = dinv[i];
    float4 o0 = make_float4(di * (a0.x + b0.x), di * (a0.y + b0.y),
                            di * (a1.x + b1.x), di * (a1.y + b1.y));
    float4 o1 = make_float4(di * (a2.x + b2.x), di * (a2.y + b2.y),
                            di * (a3.x + b3.x), di * (a3.y + b3.y));
    *(float4*)&agg2[(size_t)i * 64 + l * 8] = o0;
    *(float4*)&agg2[(size_t)i * 64 + l * 8 + 4] = o1;
}

// ---------- fused transforms 64->64(ReLU)->5, register-tiled ----------
// 64-row tile, 256 threads = 16 rowquads x 16 colquads, 4x4 register tile.
// rowsL reused for h3 between phases. zs = dinv * (h3 @ W4).
__global__ __launch_bounds__(256) void k_t3(const float* __restrict__ agg2,
                                            const float* __restrict__ W3, const float* __restrict__ b3,
                                            const float* __restrict__ W4, const float* __restrict__ dinv,
                                            float* __restrict__ zs, int N) {
    __shared__ alignas(16) float sW3[64 * 64];   // 16 KB
    __shared__ float sb3[64];
    __shared__ float sW4[64 * 5];
    __shared__ float rowsL[64][65];              // 16.6 KB; odd pad -> distinct banks
    int r0 = blockIdx.x * 64;
    for (int k = threadIdx.x; k < 64 * 64; k += 256) sW3[k] = W3[k];
    if (threadIdx.x < 64) sb3[threadIdx.x] = b3[threadIdx.x];
    for (int k = threadIdx.x; k < 320; k += 256) sW4[k] = W4[k];
    for (int idx = threadIdx.x; idx < 64 * 64; idx += 256) {
        int r = idx >> 6, d = idx & 63;
        int gi = r0 + r;
        rowsL[r][d] = (gi < N) ? agg2[(size_t)gi * 64 + d] : 0.0f;
    }
    __syncthreads();
    int rq = threadIdx.x >> 4, cq = threadIdx.x & 15;
    float acc[4][4];
    #pragma unroll
    for (int r = 0; r < 4; ++r)
        #pragma unroll
        for (int c = 0; c < 4; ++c) acc[r][c] = sb3[4 * cq + c];
    for (int d = 0; d < 64; ++d) {
        float4 wv = *(const float4*)&sW3[d * 64 + 4 * cq];
        #pragma unroll
        for (int r = 0; r < 4; ++r) {
            float rv = rowsL[4 * rq + r][d];
            acc[r][0] = fmaf(rv, wv.x, acc[r][0]);
            acc[r][1] = fmaf(rv, wv.y, acc[r][1]);
            acc[r][2] = fmaf(rv, wv.z, acc[r][2]);
            acc[r][3] = fmaf(rv, wv.w, acc[r][3]);
        }
    }
    __syncthreads();   // everyone done reading rowsL
    #pragma unroll
    for (int r = 0; r < 4; ++r)
        #pragma unroll
        for (int c = 0; c < 4; ++c)
            rowsL[4 * rq + r][4 * cq + c] = fmaxf(acc[r][c], 0.0f);  // h3 into rowsL
    __syncthreads();
    for (int o = threadIdx.x; o < 320; o += 256) {
        int r = o / 5, j = o % 5;
        int gi = r0 + r;
        if (gi < N) {
            float z = 0.0f;
            #pragma unroll
            for (int d = 0; d < 64; ++d) z = fmaf(rowsL[r][d], sW4[d * 5 + j], z);
            zs[(size_t)gi * 5 + j] = dinv[gi] * z;
        }
    }
}

// ---------- agg D=5 f32 (pre-scaled) -> d_out ----------
__global__ void k_agg5(const int* __restrict__ col, const int* __restrict__ rowptr,
                       const float* __restrict__ dinv, const float* __restrict__ zs,
                       float* __restrict__ out, int N) {
    int g = threadIdx.x / 5, d = threadIdx.x % 5;   // 64 nodes per 320-block
    int i = blockIdx.x * 64 + g;
    if (i >= N || threadIdx.x >= 320) return;
    int beg = rowptr[i], end = rowptr[i + 1];
    float acc0 = zs[(size_t)i * 5 + d], acc1 = 0.0f;
    int e = beg;
    for (; e + 1 < end; e += 2) {
        int s0 = col[e], s1 = col[e + 1];
        acc0 += zs[(size_t)s0 * 5 + d];
        acc1 += zs[(size_t)s1 * 5 + d];
    }
    if (e < end) acc0 += zs[(size_t)col[e] * 5 + d];
    out[(size_t)i * 5 + d] = dinv[i] * (acc0 + acc1);
}

// ---------- final: out = log_softmax(out + b), 5 classes, in-place ----------
__global__ void k_logsoftmax5(float* __restrict__ io, const float* __restrict__ b, int N) {
    int i = blockIdx.x * blockDim.x + threadIdx.x;
    if (i >= N) return;
    float v[5];
    #pragma unroll
    for (int j = 0; j < 5; ++j) v[j] = io[(long long)i * 5 + j] + b[j];
    float m = v[0];
    #pragma unroll
    for (int j = 1; j < 5; ++j) m = fmaxf(m, v[j]);
    float s = 0.0f;
    #pragma unroll
    for (int j = 0; j < 5; ++j) s += expf(v[j] - m);
    float ls = m + logf(s);
    #pragma unroll
    for (int j = 0; j < 5; ++j) io[(long long)i * 5 + j] = v[j] - ls;
}

extern "C" void kernel_launch(void* const* d_in, const int* in_sizes, int n_in,
                              void* d_out, int out_size, void* d_ws, size_t ws_size,
                              hipStream_t stream) {
    const float* x  = (const float*)d_in[0];
    const int*   ei = (const int*)d_in[1];   // [2, E] int32
    const float* W1 = (const float*)d_in[2];
    const float* b1 = (const float*)d_in[3];
    const float* W2 = (const float*)d_in[4];
    const float* b2 = (const float*)d_in[5];
    const float* W3 = (const float*)d_in[6];
    const float* b3 = (const float*)d_in[7];
    const float* W4 = (const float*)d_in[8];
    const float* b4 = (const float*)d_in[9];

    const int N = in_sizes[0];        // 100000
    const int E = in_sizes[1] / 2;    // 3200000
    float* out = (float*)d_out;
    const int* src = ei;
    const int* dst = ei + E;
    (void)n_in; (void)out_size; (void)ws_size;

    const int NB = (N + 255) >> 8;    // 391 buckets

    // ---- workspace layout (256B aligned; ~65.2MB, same proven footprint) ----
    auto align_up = [](size_t v) { return (v + 255) & ~(size_t)255; };
    char* p = (char*)d_ws;
    int*      rowptr = (int*)p;      p += align_up(sizeof(int) * (size_t)(N + 1));
    float*    dinv   = (float*)p;    p += align_up(sizeof(float) * (size_t)N);
    int*      bcnt   = (int*)p;      p += align_up(sizeof(int) * (MAXNB + 1));
    int*      bbase  = (int*)p;      p += align_up(sizeof(int) * (MAXNB + 1));
    int*      bcur   = (int*)p;      p += align_up(sizeof(int) * (MAXNB + 1));
    float*    g0     = (float*)p;    p += align_up(sizeof(float) * (size_t)N);
    int*      col    = (int*)p;      p += align_up(sizeof(int) * (size_t)E);
    unsigned* g2     = (unsigned*)p; p += align_up(sizeof(unsigned) * (size_t)N * 32);
    float*    agg2   = (float*)p;    p += align_up(sizeof(float) * (size_t)N * 64);
    char*     X      = p;            p += align_up(sizeof(int) * (size_t)E);
    // region X: ebuf (build) -> agg1 (N*16 f32 @0) + g1 (N*8 u32 @ +N*16*4)
    int*      ebuf   = (int*)X;
    float*    agg1   = (float*)X;
    unsigned* g1     = (unsigned*)(X + align_up(sizeof(float) * (size_t)N * 16));
    float*    zs     = (float*)g2;   // g2 dead after k_aggh64; zs = N*5 f32

    // ---- CSR build (bucketed) ----
    constexpr int ITER = 32;
    const int gBkt = nblk(E, BLK * ITER);
    k_zero_i32<<<nblk(NB), BLK, 0, stream>>>(bcnt, NB);
    k_bucket_hist<ITER><<<gBkt, BLK, 0, stream>>>(dst, bcnt, E, NB);
    k_bucket_scan<<<1, 512, 0, stream>>>(bcnt, bbase, bcur, NB);
    k_bin<ITER><<<gBkt, BLK, 0, stream>>>(src, dst, bcur, ebuf, E, NB);
    k_build<<<NB, 512, 0, stream>>>(bbase, ebuf, rowptr, dinv, x, g0, col, N);

    // ---- L1: fused agg + 1->16 -> g1 (half2, scaled) ----
    k_agg1_t16<<<nblk(N), BLK, 0, stream>>>(col, rowptr, dinv, g0, W1, b1, g1, N);

    // ---- L2: agg16 -> agg1 f32; transform 16->64 -> g2 (half2, scaled) ----
    k_aggh16<<<nblk(N, 64), 256, 0, stream>>>(col, rowptr, dinv, (const uint2*)g1, agg1, N);
    k_t2v2<<<nblk(N, 64), 256, 0, stream>>>(agg1, W2, b2, dinv, g2, N);

    // ---- L3: agg64 -> agg2 f32; fused 64->64->5 -> zs f32 (scaled) ----
    k_aggh64<<<nblk(N, 32), 256, 0, stream>>>(col, rowptr, dinv, (const uint4*)g2, agg2, N);
    k_t3<<<nblk(N, 64), 256, 0, stream>>>(agg2, W3, b3, W4, dinv, zs, N);

    // ---- L4: agg5 -> out; logsoftmax ----
    k_agg5<<<nblk(N, 64), 320, 0, stream>>>(col, rowptr, dinv, zs, out, N);
    k_logsoftmax5<<<nblk(N), BLK, 0, stream>>>(out, b4, N);
}